// Round 1
// baseline (40.435 us; speedup 1.0000x reference)
//
#include <hip/hip_runtime.h>

typedef __attribute__((ext_vector_type(8))) short bf16x8;
typedef __attribute__((ext_vector_type(4))) float f32x4;
typedef __attribute__((ext_vector_type(4))) unsigned int u32x4;

#define DD 1024
#define KC 256
#define BM 64
#define BK 64
#define KSTEPS (DD / BK)
#define CLAMP_EPS 1e-8f

__device__ __forceinline__ unsigned short f2bf(float f) {
  unsigned int u = __float_as_uint(f);
  u += 0x7FFFu + ((u >> 16) & 1u);   // RNE (inputs are finite normals)
  return (unsigned short)(u >> 16);
}

// Kernel 1: per-center inverse-norm + prenormalized bf16 copy into ws.
// One wave per center row (256 blocks x 64 lanes); lane owns 16 contiguous floats.
__global__ __launch_bounds__(64) void center_norm_kernel(
    const float* __restrict__ c, short* __restrict__ cn) {
  const int k = blockIdx.x;
  const int lane = threadIdx.x;
  const float* row = c + (size_t)k * DD + lane * 16;
  f32x4 v0 = *(const f32x4*)(row);
  f32x4 v1 = *(const f32x4*)(row + 4);
  f32x4 v2 = *(const f32x4*)(row + 8);
  f32x4 v3 = *(const f32x4*)(row + 12);
  float ss = 0.f;
  #pragma unroll
  for (int j = 0; j < 4; ++j)
    ss += v0[j]*v0[j] + v1[j]*v1[j] + v2[j]*v2[j] + v3[j]*v3[j];
  #pragma unroll
  for (int off = 32; off > 0; off >>= 1) ss += __shfl_xor(ss, off, 64);
  const float inv = 1.f / fmaxf(sqrtf(ss), CLAMP_EPS);
  bf16x8 lo, hi;
  #pragma unroll
  for (int j = 0; j < 4; ++j) {
    lo[j]     = (short)f2bf(v0[j] * inv);
    lo[j + 4] = (short)f2bf(v1[j] * inv);
    hi[j]     = (short)f2bf(v2[j] * inv);
    hi[j + 4] = (short)f2bf(v3[j] * inv);
  }
  short* o = cn + (size_t)k * DD + lane * 16;
  *(bf16x8*)o = lo;
  *(bf16x8*)(o + 8) = hi;
}

// Kernel 2: fused GEMM. BM=64 rows x BN=256 centers per block, BK=64.
// A (fp32 x) reg-staged -> ssq accumulate -> bf16 -> swizzled LDS.
// B (prenormalized bf16) reg-staged -> swizzled LDS.
// Epilogue: out = 0.5 * dot * invnorm_x + 0.5
__global__ __launch_bounds__(512) void cossim_gemm_kernel(
    const float* __restrict__ x, const short* __restrict__ cn,
    float* __restrict__ out) {
  __shared__ __align__(16) short As[BM * BK];   // 8 KB, XOR-swizzled
  __shared__ __align__(16) short Bs[KC * BK];   // 32 KB, XOR-swizzled
  __shared__ float red[512];
  __shared__ float invx[BM];

  const int t = threadIdx.x;
  const int lane = t & 63;
  const int wid = t >> 6;
  const int wm = wid >> 2;   // 0..1  -> 32-row slab
  const int wn = wid & 3;    // 0..3  -> 64-col slab
  const int row0 = blockIdx.x * BM;

  // A staging: thread owns row (t>>3), 8-float segment (t&7) — fixed across K
  const int ar = t >> 3;
  const int aseg = t & 7;
  const float* aptr = x + (size_t)(row0 + ar) * DD + aseg * 8;

  // B staging: 4 flattened 16B chunks per thread, fully coalesced
  int bn[4], bk[4];
  const short* bptr[4];
  #pragma unroll
  for (int i = 0; i < 4; ++i) {
    const int g = i * 512 + t;          // 0..2047 chunks of 8 bf16
    bn[i] = g >> 3;                     // center row 0..255
    bk[i] = g & 7;                      // chunk within BK
    bptr[i] = cn + (size_t)bn[i] * DD + bk[i] * 8;
  }

  f32x4 acc[2][4];
  #pragma unroll
  for (int i = 0; i < 2; ++i)
    #pragma unroll
    for (int j = 0; j < 4; ++j) acc[i][j] = (f32x4)(0.f);

  float ssq = 0.f;

  // prefetch K-step 0
  f32x4 a0 = *(const f32x4*)(aptr);
  f32x4 a1 = *(const f32x4*)(aptr + 4);
  u32x4 b[4];
  #pragma unroll
  for (int i = 0; i < 4; ++i) b[i] = *(const u32x4*)(bptr[i]);

  const int sA = (ar * BK + aseg * 8) ^ ((ar & 7) << 3);
  int sB[4];
  #pragma unroll
  for (int i = 0; i < 4; ++i)
    sB[i] = (bn[i] * BK + bk[i] * 8) ^ ((bn[i] & 7) << 3);

  for (int ks = 0; ks < KSTEPS; ++ks) {
    __syncthreads();   // previous MFMA phase done reading LDS
    // accumulate fp32 sum-of-squares for this row segment
    #pragma unroll
    for (int j = 0; j < 4; ++j) ssq += a0[j]*a0[j] + a1[j]*a1[j];
    // convert + swizzled LDS write
    bf16x8 av;
    #pragma unroll
    for (int j = 0; j < 4; ++j) {
      av[j]     = (short)f2bf(a0[j]);
      av[j + 4] = (short)f2bf(a1[j]);
    }
    *(bf16x8*)&As[sA] = av;
    #pragma unroll
    for (int i = 0; i < 4; ++i) *(u32x4*)&Bs[sB[i]] = b[i];
    // prefetch next K-step (overlaps with MFMA below up to barrier drain)
    if (ks + 1 < KSTEPS) {
      const float* ap = aptr + (ks + 1) * BK;
      a0 = *(const f32x4*)(ap);
      a1 = *(const f32x4*)(ap + 4);
      #pragma unroll
      for (int i = 0; i < 4; ++i)
        b[i] = *(const u32x4*)(bptr[i] + (ks + 1) * BK);
    }
    __syncthreads();   // LDS tiles ready
    #pragma unroll
    for (int ksub = 0; ksub < 2; ++ksub) {
      bf16x8 af[2], bfr[4];
      const int kk = ksub * 32 + (lane >> 4) * 8;
      #pragma unroll
      for (int fm = 0; fm < 2; ++fm) {
        const int rl = wm * 32 + fm * 16 + (lane & 15);
        af[fm] = *(const bf16x8*)&As[(rl * BK + kk) ^ ((rl & 7) << 3)];
      }
      #pragma unroll
      for (int fn = 0; fn < 4; ++fn) {
        const int nl = wn * 64 + fn * 16 + (lane & 15);
        bfr[fn] = *(const bf16x8*)&Bs[(nl * BK + kk) ^ ((nl & 7) << 3)];
      }
      #pragma unroll
      for (int fm = 0; fm < 2; ++fm)
        #pragma unroll
        for (int fn = 0; fn < 4; ++fn)
          acc[fm][fn] = __builtin_amdgcn_mfma_f32_16x16x32_bf16(
              af[fm], bfr[fn], acc[fm][fn], 0, 0, 0);
    }
  }

  // reduce per-row sum-of-squares (8 partials per row)
  red[t] = ssq;
  __syncthreads();
  if (t < BM) {
    float s = 0.f;
    #pragma unroll
    for (int j = 0; j < 8; ++j) s += red[t * 8 + j];
    invx[t] = 1.f / fmaxf(sqrtf(s), CLAMP_EPS);
  }
  __syncthreads();

  // epilogue: C/D layout col=lane&15, row=(lane>>4)*4+reg  [m89]
  #pragma unroll
  for (int fm = 0; fm < 2; ++fm) {
    #pragma unroll
    for (int r = 0; r < 4; ++r) {
      const int rl = wm * 32 + fm * 16 + (lane >> 4) * 4 + r;
      const float inv = invx[rl];
      float* orow = out + (size_t)(row0 + rl) * KC + wn * 64 + (lane & 15);
      #pragma unroll
      for (int fn = 0; fn < 4; ++fn)
        orow[fn * 16] = fmaf(acc[fm][fn][r] * inv, 0.5f, 0.5f);
    }
  }
}

extern "C" void kernel_launch(void* const* d_in, const int* in_sizes, int n_in,
                              void* d_out, int out_size, void* d_ws, size_t ws_size,
                              hipStream_t stream) {
  const float* x = (const float*)d_in[0];
  const float* c = (const float*)d_in[1];
  float* out = (float*)d_out;
  short* cn = (short*)d_ws;              // 256*1024 bf16 = 512 KB

  const int nrows = in_sizes[0] / DD;    // 32768
  center_norm_kernel<<<KC, 64, 0, stream>>>(c, cn);
  cossim_gemm_kernel<<<nrows / BM, 512, 0, stream>>>(x, cn, out);
}